// Round 4
// baseline (106.288 us; speedup 1.0000x reference)
//
#include <hip/hip_runtime.h>
#include <hip/hip_cooperative_groups.h>

namespace cg = cooperative_groups;

// Cox time-dependent loss, single cooperative kernel (3 phases).
// loss = -(sum ev*e) + sum_b histC[b]*log(inclE[b]),
// inclE = flipped prefix sum of per-bin sum of exp(r), B=4096 bins.
// R3 showed ~28us of inter-dispatch overhead vs ~13us of real work -> fuse.

constexpr int B = 4096;
constexpr float TMAX = 1000.0f;
constexpr int BLOCKS = 256;
constexpr int THREADS = 1024;

__device__ __forceinline__ int flip_bin(float t) {
    float x = t * ((float)B / TMAX);
    int b = (int)x;
    b = b < 0 ? 0 : (b > B - 1 ? B - 1 : b);
    return (B - 1) - b;                 // flipped: suffix-sum -> prefix-sum
}

__global__ __launch_bounds__(THREADS)
void cox_fused_kernel(const float* __restrict__ risk,
                      const float* __restrict__ yraw,
                      float* __restrict__ pE, unsigned short* __restrict__ pC,
                      float* __restrict__ seePartial,
                      float* __restrict__ histE, float* __restrict__ histC,
                      float* __restrict__ out, int n)
{
    __shared__ __align__(16) float hE[B];          // 16 KB (reused each phase)
    __shared__ __align__(16) unsigned int hC[B];   // 16 KB (reused each phase)
    __shared__ float wsum[THREADS / 64];
    const int tid = threadIdx.x;
    const int bid = blockIdx.x;

    // ---- phase 1: per-block LDS histograms + sum(ev*exp(r)) ----
    for (int i = tid; i < B; i += THREADS) { hE[i] = 0.f; hC[i] = 0u; }
    __syncthreads();

    const float4* risk4 = (const float4*)risk;
    const float4* y4 = (const float4*)yraw;
    const int n4 = n >> 2;
    const int gsz = gridDim.x * blockDim.x;
    float see = 0.f;
    for (int i = bid * THREADS + tid; i < n4; i += gsz) {
        float4 r  = risk4[i];
        float4 ya = y4[2 * i];          // (t0,ev0,t1,ev1)
        float4 yb = y4[2 * i + 1];      // (t2,ev2,t3,ev3)
        float e0 = __expf(r.x), e1 = __expf(r.y);
        float e2 = __expf(r.z), e3 = __expf(r.w);
        int b0 = flip_bin(ya.x), b1 = flip_bin(ya.z);
        int b2 = flip_bin(yb.x), b3 = flip_bin(yb.z);
        atomicAdd(&hE[b0], e0);
        atomicAdd(&hE[b1], e1);
        atomicAdd(&hE[b2], e2);
        atomicAdd(&hE[b3], e3);
        if (ya.y != 0.f) { atomicAdd(&hC[b0], 1u); see += e0; }
        if (ya.w != 0.f) { atomicAdd(&hC[b1], 1u); see += e1; }
        if (yb.y != 0.f) { atomicAdd(&hC[b2], 1u); see += e2; }
        if (yb.w != 0.f) { atomicAdd(&hC[b3], 1u); see += e3; }
    }
    if (bid == 0 && tid < (n & 3)) {    // scalar tail
        int i = (n4 << 2) + tid;
        float e = __expf(risk[i]);
        float t = yraw[2 * i], ev = yraw[2 * i + 1];
        atomicAdd(&hE[flip_bin(t)], e);
        if (ev != 0.f) { atomicAdd(&hC[flip_bin(t)], 1u); see += e; }
    }

    #pragma unroll
    for (int off = 32; off > 0; off >>= 1) see += __shfl_down(see, off, 64);
    if ((tid & 63) == 0) wsum[tid >> 6] = see;
    __syncthreads();
    if (tid == 0) {
        float s = 0.f;
        #pragma unroll
        for (int w = 0; w < THREADS / 64; ++w) s += wsum[w];
        seePartial[bid] = s;
    }

    float* oE = pE + (size_t)bid * B;
    unsigned short* oC = pC + (size_t)bid * B;
    for (int i = tid; i < B; i += THREADS) {
        oE[i] = hE[i];
        oC[i] = (unsigned short)hC[i];
    }

    cg::this_grid().sync();

    // ---- phase 2: block b reduces bins [b*16, b*16+16) over 256 copies ----
    {
        const int binOff = tid & 15;
        const int cl = tid >> 4;                // 0..63 copy-lane
        const int bin = bid * 16 + binOff;
        float sE = 0.f, sC = 0.f;
        #pragma unroll
        for (int k = 0; k < BLOCKS / 64; ++k) {
            int c = cl + 64 * k;
            sE += pE[(size_t)c * B + bin];
            sC += (float)pC[(size_t)c * B + bin];
        }
        float* smE = hE;                        // reuse LDS
        float* smC = (float*)hC;
        smE[cl * 16 + binOff] = sE;
        smC[cl * 16 + binOff] = sC;
        __syncthreads();
        #pragma unroll
        for (int off = 32; off >= 1; off >>= 1) {
            if (cl < off) {
                smE[cl * 16 + binOff] += smE[(cl + off) * 16 + binOff];
                smC[cl * 16 + binOff] += smC[(cl + off) * 16 + binOff];
            }
            __syncthreads();
        }
        if (tid < 16) {
            histE[bid * 16 + tid] = smE[tid];
            histC[bid * 16 + tid] = smC[tid];
        }
    }

    cg::this_grid().sync();

    // ---- phase 3 (block 0): scan histE, dot with histC*log, minus see ----
    if (bid == 0) {
        float* s = hE;                          // reuse LDS
        double* sd = (double*)hC;               // 1024 doubles in 16 KB
        float4 a = ((const float4*)histE)[tid];
        float s0 = a.x;
        float s1 = s0 + a.y;
        float s2 = s1 + a.z;
        float s3 = s2 + a.w;
        s[tid] = s3;
        __syncthreads();
        for (int off = 1; off < 1024; off <<= 1) {
            float t_ = (tid >= off) ? s[tid - off] : 0.f;
            __syncthreads();
            s[tid] += t_;
            __syncthreads();
        }
        float excl = s[tid] - s3;
        float4 c = ((const float4*)histC)[tid];
        float p = 0.f;
        p += c.x * __logf(fmaxf(excl + s0, 1e-35f));
        p += c.y * __logf(fmaxf(excl + s1, 1e-35f));
        p += c.z * __logf(fmaxf(excl + s2, 1e-35f));
        p += c.w * __logf(fmaxf(excl + s3, 1e-35f));

        double v = (double)p;
        if (tid < BLOCKS) v -= (double)seePartial[tid];
        sd[tid] = v;
        __syncthreads();
        #pragma unroll
        for (int off = 512; off > 0; off >>= 1) {
            if (tid < off) sd[tid] += sd[tid + off];
            __syncthreads();
        }
        if (tid == 0) out[0] = (float)sd[0];
    }
}

// ---------- fallback (non-cooperative 3-kernel path, R3 pipeline) ----------
__global__ __launch_bounds__(THREADS)
void hist_kernel(const float4* __restrict__ risk4, const float4* __restrict__ y4,
                 float* __restrict__ pE, unsigned short* __restrict__ pC,
                 float* __restrict__ seePartial, int n) {
    __shared__ float hE[B];
    __shared__ unsigned int hC[B];
    __shared__ float wsum[THREADS / 64];
    const int tid = threadIdx.x;
    for (int i = tid; i < B; i += THREADS) { hE[i] = 0.f; hC[i] = 0u; }
    __syncthreads();
    const int n4 = n >> 2;
    const int gsz = gridDim.x * blockDim.x;
    float see = 0.f;
    for (int i = blockIdx.x * blockDim.x + tid; i < n4; i += gsz) {
        float4 r = risk4[i];
        float4 ya = y4[2 * i];
        float4 yb = y4[2 * i + 1];
        float e0 = __expf(r.x), e1 = __expf(r.y);
        float e2 = __expf(r.z), e3 = __expf(r.w);
        int b0 = flip_bin(ya.x), b1 = flip_bin(ya.z);
        int b2 = flip_bin(yb.x), b3 = flip_bin(yb.z);
        atomicAdd(&hE[b0], e0); atomicAdd(&hE[b1], e1);
        atomicAdd(&hE[b2], e2); atomicAdd(&hE[b3], e3);
        if (ya.y != 0.f) { atomicAdd(&hC[b0], 1u); see += e0; }
        if (ya.w != 0.f) { atomicAdd(&hC[b1], 1u); see += e1; }
        if (yb.y != 0.f) { atomicAdd(&hC[b2], 1u); see += e2; }
        if (yb.w != 0.f) { atomicAdd(&hC[b3], 1u); see += e3; }
    }
    #pragma unroll
    for (int off = 32; off > 0; off >>= 1) see += __shfl_down(see, off, 64);
    if ((tid & 63) == 0) wsum[tid >> 6] = see;
    __syncthreads();
    if (tid == 0) {
        float s = 0.f;
        #pragma unroll
        for (int w = 0; w < THREADS / 64; ++w) s += wsum[w];
        seePartial[blockIdx.x] = s;
    }
    float* oE = pE + (size_t)blockIdx.x * B;
    unsigned short* oC = pC + (size_t)blockIdx.x * B;
    for (int i = tid; i < B; i += THREADS) { oE[i] = hE[i]; oC[i] = (unsigned short)hC[i]; }
}

__global__ __launch_bounds__(256)
void reduce_hist_kernel(const float* __restrict__ pE, const unsigned short* __restrict__ pC,
                        float* __restrict__ histE, float* __restrict__ histC) {
    const int binBase = blockIdx.x * 16;
    const int binOff = threadIdx.x & 15;
    const int lane = threadIdx.x >> 4;
    const int bin = binBase + binOff;
    float sE = 0.f, sC = 0.f;
    for (int c = lane; c < BLOCKS; c += 16) {
        sE += pE[(size_t)c * B + bin];
        sC += (float)pC[(size_t)c * B + bin];
    }
    __shared__ float smE[256], smC[256];
    smE[threadIdx.x] = sE; smC[threadIdx.x] = sC;
    __syncthreads();
    if (threadIdx.x < 16) {
        float aE = 0.f, aC = 0.f;
        #pragma unroll
        for (int l = 0; l < 16; ++l) { aE += smE[l * 16 + threadIdx.x]; aC += smC[l * 16 + threadIdx.x]; }
        histE[binBase + threadIdx.x] = aE;
        histC[binBase + threadIdx.x] = aC;
    }
}

__global__ __launch_bounds__(1024)
void scan_dot_kernel(const float* __restrict__ histE, const float* __restrict__ histC,
                     const float* __restrict__ seePartial, float* __restrict__ out) {
    __shared__ float s[1024];
    __shared__ double sd[1024];
    const int tid = threadIdx.x;
    float4 a = ((const float4*)histE)[tid];
    float s0 = a.x, s1 = s0 + a.y, s2 = s1 + a.z, s3 = s2 + a.w;
    s[tid] = s3;
    __syncthreads();
    for (int off = 1; off < 1024; off <<= 1) {
        float t_ = (tid >= off) ? s[tid - off] : 0.f;
        __syncthreads();
        s[tid] += t_;
        __syncthreads();
    }
    float excl = s[tid] - s3;
    float4 c = ((const float4*)histC)[tid];
    float p = c.x * __logf(fmaxf(excl + s0, 1e-35f))
            + c.y * __logf(fmaxf(excl + s1, 1e-35f))
            + c.z * __logf(fmaxf(excl + s2, 1e-35f))
            + c.w * __logf(fmaxf(excl + s3, 1e-35f));
    double v = (double)p;
    if (tid < BLOCKS) v -= (double)seePartial[tid];
    sd[tid] = v;
    __syncthreads();
    #pragma unroll
    for (int off = 512; off > 0; off >>= 1) {
        if (tid < off) sd[tid] += sd[tid + off];
        __syncthreads();
    }
    if (tid == 0) out[0] = (float)sd[0];
}

extern "C" void kernel_launch(void* const* d_in, const int* in_sizes, int n_in,
                              void* d_out, int out_size, void* d_ws, size_t ws_size,
                              hipStream_t stream) {
    const float* risk = (const float*)d_in[0];
    const float* yraw = (const float*)d_in[1];
    int n = in_sizes[0];

    float* pE            = (float*)d_ws;                                    // 4 MB
    unsigned short* pC   = (unsigned short*)(pE + (size_t)BLOCKS * B);      // 2 MB
    float* histE         = (float*)(pC + (size_t)BLOCKS * B);
    float* histC         = histE + B;
    float* seePartial    = histC + B;
    float* out           = (float*)d_out;

    void* args[] = { (void*)&risk, (void*)&yraw, (void*)&pE, (void*)&pC,
                     (void*)&seePartial, (void*)&histE, (void*)&histC,
                     (void*)&out, (void*)&n };
    hipError_t err = hipLaunchCooperativeKernel((const void*)cox_fused_kernel,
                                                dim3(BLOCKS), dim3(THREADS),
                                                args, 0, stream);
    if (err != hipSuccess) {
        // fallback: 3-kernel pipeline
        hist_kernel<<<BLOCKS, THREADS, 0, stream>>>((const float4*)risk, (const float4*)yraw,
                                                    pE, pC, seePartial, n);
        reduce_hist_kernel<<<B / 16, 256, 0, stream>>>(pE, pC, histE, histC);
        scan_dot_kernel<<<1, 1024, 0, stream>>>(histE, histC, seePartial, out);
    }
}

// Round 5
// 45.629 us; speedup vs baseline: 2.3294x; 2.3294x over previous
//
#include <hip/hip_runtime.h>

// Cox time-dependent loss, 3-kernel pipeline (R3 structure), inputs read once.
// loss = -(sum ev*e) + sum_b histC[b]*log(inclE[b]),
// inclE = flipped prefix sum of per-bin sum of exp(r).
// R4 lesson: cooperative grid.sync costs ~25+us/barrier on MI355X (XCD cache
// flush + spin) -> fused kernel regressed. Launch gaps are only ~2us; the
// remaining lever is hist occupancy: B=2048 (16.25KB LDS) + 512 blocks gives
// 2 x 1024-thread blocks/CU = 32 waves/CU (was 16).

constexpr int B = 2048;
constexpr float TMAX = 1000.0f;
constexpr int HIST_BLOCKS = 512;
constexpr int HIST_THREADS = 1024;

__device__ __forceinline__ int flip_bin(float t) {
    float x = t * ((float)B / TMAX);
    int b = (int)x;
    b = b < 0 ? 0 : (b > B - 1 ? B - 1 : b);
    return (B - 1) - b;                 // flipped: suffix-sum -> prefix-sum
}

// Pass 1: per-block LDS histograms (E = sum exp(r), C = event count) + sum(ev*e).
__global__ __launch_bounds__(HIST_THREADS)
void hist_kernel(const float4* __restrict__ risk4,
                 const float4* __restrict__ y4,      // pairs of (t,ev)
                 float* __restrict__ pE, unsigned short* __restrict__ pC,
                 float* __restrict__ seePartial, int n) {
    __shared__ float hE[B];
    __shared__ unsigned int hC[B];
    __shared__ float wsum[HIST_THREADS / 64];
    const int tid = threadIdx.x;
    for (int i = tid; i < B; i += HIST_THREADS) { hE[i] = 0.f; hC[i] = 0u; }
    __syncthreads();

    const int n4 = n >> 2;
    const int gsz = gridDim.x * blockDim.x;
    float see = 0.f;
    for (int i = blockIdx.x * blockDim.x + tid; i < n4; i += gsz) {
        float4 r  = risk4[i];
        float4 ya = y4[2 * i];          // (t0,ev0,t1,ev1)
        float4 yb = y4[2 * i + 1];      // (t2,ev2,t3,ev3)
        float e0 = __expf(r.x), e1 = __expf(r.y);
        float e2 = __expf(r.z), e3 = __expf(r.w);
        int b0 = flip_bin(ya.x), b1 = flip_bin(ya.z);
        int b2 = flip_bin(yb.x), b3 = flip_bin(yb.z);
        atomicAdd(&hE[b0], e0);
        atomicAdd(&hE[b1], e1);
        atomicAdd(&hE[b2], e2);
        atomicAdd(&hE[b3], e3);
        if (ya.y != 0.f) { atomicAdd(&hC[b0], 1u); see += e0; }
        if (ya.w != 0.f) { atomicAdd(&hC[b1], 1u); see += e1; }
        if (yb.y != 0.f) { atomicAdd(&hC[b2], 1u); see += e2; }
        if (yb.w != 0.f) { atomicAdd(&hC[b3], 1u); see += e3; }
    }
    // scalar tail (n % 4) — n=4194304 is divisible, kept for safety
    if (blockIdx.x == 0 && tid < (n & 3)) {
        int i = (n4 << 2) + tid;
        const float* risk = (const float*)risk4;
        const float* yraw = (const float*)y4;
        float e = __expf(risk[i]);
        float t = yraw[2 * i], ev = yraw[2 * i + 1];
        int b = flip_bin(t);
        atomicAdd(&hE[b], e);
        if (ev != 0.f) { atomicAdd(&hC[b], 1u); see += e; }
    }

    #pragma unroll
    for (int off = 32; off > 0; off >>= 1) see += __shfl_down(see, off, 64);
    if ((tid & 63) == 0) wsum[tid >> 6] = see;
    __syncthreads();
    if (tid == 0) {
        float s = 0.f;
        #pragma unroll
        for (int w = 0; w < HIST_THREADS / 64; ++w) s += wsum[w];
        seePartial[blockIdx.x] = s;
    }

    float* oE = pE + (size_t)blockIdx.x * B;
    unsigned short* oC = pC + (size_t)blockIdx.x * B;
    for (int i = tid; i < B; i += HIST_THREADS) {
        oE[i] = hE[i];
        oC[i] = (unsigned short)hC[i];   // per-block bin count <= 8192, fits
    }
}

// Pass 2: reduce 512 partial copies -> histE[B], histC[B] (as float).
// 128 blocks x 256 threads; block b owns bins [b*16, b*16+16).
__global__ __launch_bounds__(256)
void reduce_hist_kernel(const float* __restrict__ pE,
                        const unsigned short* __restrict__ pC,
                        float* __restrict__ histE, float* __restrict__ histC) {
    const int binBase = blockIdx.x * 16;
    const int binOff = threadIdx.x & 15;
    const int lane = threadIdx.x >> 4;      // 0..15
    const int bin = binBase + binOff;

    float sE = 0.f, sC = 0.f;
    for (int c = lane; c < HIST_BLOCKS; c += 16) {
        sE += pE[(size_t)c * B + bin];
        sC += (float)pC[(size_t)c * B + bin];
    }
    __shared__ float smE[256], smC[256];
    smE[threadIdx.x] = sE;
    smC[threadIdx.x] = sC;
    __syncthreads();
    if (threadIdx.x < 16) {
        float aE = 0.f, aC = 0.f;
        #pragma unroll
        for (int l = 0; l < 16; ++l) {
            aE += smE[l * 16 + threadIdx.x];
            aC += smC[l * 16 + threadIdx.x];
        }
        histE[binBase + threadIdx.x] = aE;
        histC[binBase + threadIdx.x] = aC;
    }
}

// Pass 3 (1 block, 512 threads): scan histE, dot with histC*log, minus see.
__global__ __launch_bounds__(512)
void scan_dot_kernel(const float* __restrict__ histE,
                     const float* __restrict__ histC,
                     const float* __restrict__ seePartial,
                     float* __restrict__ out) {
    __shared__ float s[512];
    __shared__ double sd[512];
    const int tid = threadIdx.x;

    float4 a = ((const float4*)histE)[tid];
    float s0 = a.x;
    float s1 = s0 + a.y;
    float s2 = s1 + a.z;
    float s3 = s2 + a.w;
    s[tid] = s3;
    __syncthreads();
    for (int off = 1; off < 512; off <<= 1) {
        float t_ = (tid >= off) ? s[tid - off] : 0.f;
        __syncthreads();
        s[tid] += t_;
        __syncthreads();
    }
    float excl = s[tid] - s3;
    float4 c = ((const float4*)histC)[tid];
    float p = c.x * __logf(fmaxf(excl + s0, 1e-35f))
            + c.y * __logf(fmaxf(excl + s1, 1e-35f))
            + c.z * __logf(fmaxf(excl + s2, 1e-35f))
            + c.w * __logf(fmaxf(excl + s3, 1e-35f));

    double v = (double)p - (double)seePartial[tid];  // 512 partials, 512 threads
    sd[tid] = v;
    __syncthreads();
    #pragma unroll
    for (int off = 256; off > 0; off >>= 1) {
        if (tid < off) sd[tid] += sd[tid + off];
        __syncthreads();
    }
    if (tid == 0) out[0] = (float)sd[0];
}

extern "C" void kernel_launch(void* const* d_in, const int* in_sizes, int n_in,
                              void* d_out, int out_size, void* d_ws, size_t ws_size,
                              hipStream_t stream) {
    const float4* risk4 = (const float4*)d_in[0];
    const float4* y4    = (const float4*)d_in[1];
    const int n = in_sizes[0];

    float* pE            = (float*)d_ws;                                    // 512*2048 f = 4MB
    unsigned short* pC   = (unsigned short*)(pE + (size_t)HIST_BLOCKS * B); // 2MB
    float* histE         = (float*)(pC + (size_t)HIST_BLOCKS * B);          // 2048 f
    float* histC         = histE + B;                                       // 2048 f
    float* seePartial    = histC + B;                                       // 512 f

    hist_kernel<<<HIST_BLOCKS, HIST_THREADS, 0, stream>>>(risk4, y4, pE, pC, seePartial, n);
    reduce_hist_kernel<<<B / 16, 256, 0, stream>>>(pE, pC, histE, histC);
    scan_dot_kernel<<<1, 512, 0, stream>>>(histE, histC, seePartial, (float*)d_out);
}